// Round 1
// 820.544 us; speedup vs baseline: 1.1079x; 1.1079x over previous
//
#include <hip/hip_runtime.h>
#include <hip/hip_fp16.h>
#include <math.h>

#define NPTS 2048
#define NB 64
#define H 8
#define DH 64
#define INNER 512

__device__ __forceinline__ float gelu_exact(float x) {
  return 0.5f * x * (1.0f + erff(x * 0.7071067811865475f));
}

__device__ __forceinline__ unsigned int pack_cs(float c, float s) {
  __half2 h = __floats2half2_rn(c, s);
  return *reinterpret_cast<unsigned int*>(&h);
}
__device__ __forceinline__ float2 unpack_cs(unsigned int u) {
  __half2 h = *reinterpret_cast<__half2*>(&u);
  return __half22float2(h);
}
__device__ __forceinline__ float2 h2_to_f2(unsigned int u) {
  __half2 h = *reinterpret_cast<__half2*>(&u);
  return __half22float2(h);
}

// ---------------- fp32 tiled GEMM: C[M,N] = A[M,K]@B[K,N] (+bias) ----------------
// If kvh != nullptr, tiles with n0 >= 512 also store fp16 copies to kvh[m][n-512]
// (the k,v halves of qkv, used by the fused attention's gathers at half traffic).
__global__ __launch_bounds__(256) void gemm_tiled(const float* __restrict__ A,
                                                  const float* __restrict__ B,
                                                  const float* __restrict__ bias,
                                                  float* __restrict__ C,
                                                  __half* __restrict__ kvh,
                                                  int M, int N, int K) {
  __shared__ float As[16][68];
  __shared__ float Bs[16][68];
  const int tid = threadIdx.x;
  const int tx = tid & 15;
  const int ty = tid >> 4;
  const int n0 = blockIdx.x << 6;
  const int m0 = blockIdx.y << 6;
  const int la_m = tid >> 2;
  const int la_k = (tid & 3) << 2;
  const int lb_k = tid >> 4;
  const int lb_n = (tid & 15) << 2;
  float acc[4][4] = {{0.f}};
  for (int kk = 0; kk < K; kk += 16) {
    const float4 a4 = *(const float4*)(A + (size_t)(m0 + la_m) * K + kk + la_k);
    const float4 b4 = *(const float4*)(B + (size_t)(kk + lb_k) * N + n0 + lb_n);
    As[la_k + 0][la_m] = a4.x;
    As[la_k + 1][la_m] = a4.y;
    As[la_k + 2][la_m] = a4.z;
    As[la_k + 3][la_m] = a4.w;
    *(float4*)(&Bs[lb_k][lb_n]) = b4;
    __syncthreads();
#pragma unroll
    for (int k = 0; k < 16; ++k) {
      const float4 av = *(const float4*)(&As[k][ty << 2]);
      const float4 bv = *(const float4*)(&Bs[k][tx << 2]);
      acc[0][0] += av.x * bv.x; acc[0][1] += av.x * bv.y; acc[0][2] += av.x * bv.z; acc[0][3] += av.x * bv.w;
      acc[1][0] += av.y * bv.x; acc[1][1] += av.y * bv.y; acc[1][2] += av.y * bv.z; acc[1][3] += av.y * bv.w;
      acc[2][0] += av.z * bv.x; acc[2][1] += av.z * bv.y; acc[2][2] += av.z * bv.z; acc[2][3] += av.z * bv.w;
      acc[3][0] += av.w * bv.x; acc[3][1] += av.w * bv.y; acc[3][2] += av.w * bv.z; acc[3][3] += av.w * bv.w;
    }
    __syncthreads();
  }
  const bool do_kv = (kvh != nullptr) && (n0 >= 512);
#pragma unroll
  for (int r = 0; r < 4; ++r) {
    const int m = m0 + (ty << 2) + r;
    const int nb = n0 + (tx << 2);
    float v[4];
#pragma unroll
    for (int c = 0; c < 4; ++c) {
      v[c] = acc[r][c];
      if (bias) v[c] += bias[nb + c];
      C[(size_t)m * N + nb + c] = v[c];
    }
    if (do_kv) {
      __half2 h01 = __floats2half2_rn(v[0], v[1]);
      __half2 h23 = __floats2half2_rn(v[2], v[3]);
      uint2 pk;
      pk.x = *reinterpret_cast<unsigned int*>(&h01);
      pk.y = *reinterpret_cast<unsigned int*>(&h23);
      *(uint2*)(kvh + (size_t)m * 1024 + (nb - 512)) = pk;
    }
  }
}

// ---------------- fused topk + neighborhood attention: one block per (b,i) ----------------
// topk v2: single-pass radix-select. 2048-bucket histogram over the (monotone) float
// bit pattern of the distance finds the bucket where cumulative count crosses 64;
// all keys in buckets <= B (~80 candidates) get exact ranks by counting smaller keys.
// Exact (dist_bits, index) lexicographic order == lax.top_k order (same key as v1).
// Replaces 64 serial extract-min rounds (770 ds_bpermute + 3.8k VALU per wave).
__global__ __launch_bounds__(256, 4) void fused_attn(
    const float* __restrict__ qkv, const __half* __restrict__ kvh,
    const float* __restrict__ coors, const float* __restrict__ edges,
    const float* __restrict__ W_e1, const float* __restrict__ b_e1,
    const float* __restrict__ W_e2, const float* __restrict__ b_e2,
    const float* __restrict__ W_c, const float* __restrict__ b_c,
    const float* __restrict__ W_g, const float* __restrict__ b_g,
    const float* __restrict__ coors_combine, const float* __restrict__ coors_scale,
    float* __restrict__ attn_out, float* __restrict__ coors_out) {
  __shared__ float q_s[H][68];
  __shared__ unsigned int cs_s[NB][33];           // stage B alias: hist[2048] (8192 <= 8448 B)
  __shared__ float qk_s[NB][9];
  __shared__ float qk2_s[NB][9];
  __shared__ float attn_s[NB][9];
  __shared__ __align__(16) float edg_s[NB][17];   // stage B alias: cand[544] (4352 B)
  __shared__ float rel_s[NB][4];
  __shared__ float dist_s[NB];
  __shared__ int idx_s[NB];                       // stage B scratch: wave scan sums idx_s[0..3]
  __shared__ float We1[24 * 48];
  __shared__ float We2[48 * 9];
  __shared__ float be1[48];
  __shared__ float be2[H], bcs[H], bgs[H], ccs[H];
  __shared__ float Wcs[H * H], Wgs[H * H];
  __shared__ float credx[4][3];
  __shared__ int selB_s;
  __shared__ int ccnt_s;

  const int row = blockIdx.x;
  const int b = row >> 11;
  const int tid = threadIdx.x;
  const int lane = tid & 63;
  const int wv = tid >> 6;
  const size_t qbase = (size_t)row * 1536;

  unsigned int* hist = &cs_s[0][0];
  unsigned long long* cand = reinterpret_cast<unsigned long long*>(&edg_s[0][0]);

  // ---- stage A: loads with no topk dependency (latency hides under histogram) ----
  for (int t = tid; t < 2048; t += 256) hist[t] = 0u;
  if (tid == 0) ccnt_s = 0;
  {
    int t0 = tid;
    q_s[t0 >> 6][t0 & 63] = qkv[qbase + t0];
    int t1 = tid + 256;
    q_s[t1 >> 6][t1 & 63] = qkv[qbase + t1];
  }
  for (int t = tid; t < 24 * 48; t += 256) We1[t] = W_e1[t];
  for (int t = tid; t < 48 * H; t += 256) We2[(t >> 3) * 9 + (t & 7)] = W_e2[t];
  if (tid < 48) be1[tid] = b_e1[tid];
  if (tid < H) { be2[tid] = b_e2[tid]; bcs[tid] = b_c[tid]; bgs[tid] = b_g[tid]; ccs[tid] = coors_combine[tid]; }
  if (tid < H * H) { Wcs[tid] = W_c[tid]; Wgs[tid] = W_g[tid]; }

  // ---- stage B: top-64 via radix-select ----
  const float* cb = coors + (size_t)b * NPTS * 3;
  const float cx = coors[(size_t)row * 3 + 0];
  const float cy = coors[(size_t)row * 3 + 1];
  const float cz = coors[(size_t)row * 3 + 2];

  unsigned long long keys[8];
#pragma unroll
  for (int s = 0; s < 8; ++s) {
    const int j = (s << 8) + tid;
    const float dx = cx - cb[j * 3 + 0];
    const float dy = cy - cb[j * 3 + 1];
    const float dz = cz - cb[j * 3 + 2];
    const float d = sqrtf(dx * dx + dy * dy + dz * dz);
    keys[s] = (((unsigned long long)__float_as_uint(d)) << 32) | (unsigned long long)j;
  }
  __syncthreads();  // S1: hist zeroed, ccnt zeroed, stage-A LDS visible

  // histogram: bucket = dist_bits >> 20 (monotone in key; covers ALL finite floats: < 2048)
#pragma unroll
  for (int s = 0; s < 8; ++s)
    atomicAdd(&hist[(unsigned int)(keys[s] >> 52)], 1u);
  __syncthreads();  // S2: histogram complete

  // block prefix-scan over 2048 buckets (8 per thread + wave scan + wave offsets)
  const int hb = tid << 3;
  int s_t = 0;
#pragma unroll
  for (int k = 0; k < 8; ++k) s_t += (int)hist[hb + k];
  int sc = s_t;
#pragma unroll
  for (int off = 1; off < 64; off <<= 1) {
    const int o = __shfl_up(sc, off, 64);
    if (lane >= off) sc += o;
  }
  if (lane == 63) idx_s[wv] = sc;
  __syncthreads();  // S3: wave totals visible
  int base = 0;
#pragma unroll
  for (int w = 0; w < 3; ++w)
    if (w < wv) base += idx_s[w];
  const int S = base + sc;              // inclusive cumulative count through this thread's 8 buckets
  if (S >= 64 && S - s_t < 64) {        // unique crossing thread
    int cum = S - s_t;
    int bsel = hb + 7;
#pragma unroll
    for (int k = 0; k < 8; ++k) {
      cum += (int)hist[hb + k];
      if (cum >= 64) { bsel = hb + k; break; }
    }
    selB_s = bsel;
  }
  __syncthreads();  // S4: selB visible; hist dead

  // collect candidates: every key of true rank <64 has bucket <= B (high bits monotone)
  {
    const unsigned long long limit = ((unsigned long long)(selB_s + 1)) << 52;
#pragma unroll
    for (int s = 0; s < 8; ++s) {
      if (keys[s] < limit) {
        const int p = atomicAdd(&ccnt_s, 1);
        if (p < 544) cand[p] = keys[s];
      }
    }
  }
  __syncthreads();  // S5: candidates complete

  // exact rank by counting smaller keys (keys unique: index in low bits)
  {
    const int c = min(ccnt_s, 544);
    for (int i = tid; i < c; i += 256) {
      const unsigned long long ki = cand[i];
      int r = 0;
      for (int j2 = 0; j2 < c; ++j2) r += (cand[j2] < ki) ? 1 : 0;
      if (r < 64) {
        idx_s[r] = (int)(ki & 0xffffffffull);
        dist_s[r] = __uint_as_float((unsigned int)(ki >> 32));
      }
    }
  }
  __syncthreads();  // S6 (== old B2): idx_s/dist_s visible; cand dead

  // ---- stage C: edges gather (HBM, longest latency — issue first), rel, cs table ----
  {
    const size_t ebase = (size_t)row * NPTS * 16;
#pragma unroll
    for (int s = 0; s < 4; ++s) {
      const int p = tid + (s << 8);
      const int j = p >> 4, e = p & 15;
      edg_s[j][e] = edges[ebase + (size_t)idx_s[j] * 16 + e];
    }
  }
  if (tid < NB) {
    const int jj = idx_s[tid];
    const float csc = coors_scale[0];
    const float dx = cx - cb[jj * 3 + 0];
    const float dy = cy - cb[jj * 3 + 1];
    const float dz = cz - cb[jj * 3 + 2];
    const float inv = csc / fmaxf(dist_s[tid], 1e-8f);
    rel_s[tid][0] = dx * inv;
    rel_s[tid][1] = dy * inv;
    rel_s[tid][2] = dz * inv;
  }
#pragma unroll
  for (int s = 0; s < 8; ++s) {
    const int p = tid + (s << 8);
    const int j = p >> 5, m = p & 31;
    const float t = fminf(dist_s[j] * 100.0f, 5000.0f);
    const float invf = __expf(-(float)m * 0.28782313662425575f);  // 10000^(-m/32)
    float sv, cv;
    __sincosf(t * invf, &sv, &cv);
    cs_s[j][m] = pack_cs(cv, sv);
  }
  __syncthreads();  // B3

  // ---- phase 2: qk[j][h] = q[h,:] . rotary(k_fp16[j,h,:]) ----
#pragma unroll
  for (int s = 0; s < 2; ++s) {
    const int p = tid + (s << 8);
    const int j = p >> 3, h = p & 7;
    const uint2* krow = (const uint2*)(kvh + ((size_t)b * NPTS + idx_s[j]) * 1024 + h * DH);
    float acc = 0.f;
#pragma unroll
    for (int m4 = 0; m4 < 16; ++m4) {
      const uint2 ku = krow[m4];
      const float2 k01 = h2_to_f2(ku.x);
      const float2 k23 = h2_to_f2(ku.y);
      const float4 qv = *(const float4*)(&q_s[h][m4 << 2]);
      const int m = m4 << 1;
      const float2 c0 = unpack_cs(cs_s[j][m]);
      const float2 c1 = unpack_cs(cs_s[j][m + 1]);
      acc += qv.x * (k01.x * c0.x - k01.y * c0.y) + qv.y * (k01.y * c0.x + k01.x * c0.y) +
             qv.z * (k23.x * c1.x - k23.y * c1.y) + qv.w * (k23.y * c1.x + k23.x * c1.y);
    }
    qk_s[j][h] = acc;
  }
  __syncthreads();  // B4

  // ---- phase 3: edge MLP, hidden in registers, quad-shuffle reduce ----
  {
    const int j = tid >> 2, part = tid & 3;
    float hv[12];
#pragma unroll
    for (int l = 0; l < 12; ++l) {
      const int hh = part * 12 + l;
      float a = be1[hh];
#pragma unroll
      for (int r = 0; r < 8; ++r) a += qk_s[j][r] * We1[r * 48 + hh];
#pragma unroll
      for (int r = 0; r < 16; ++r) a += edg_s[j][r] * We1[(8 + r) * 48 + hh];
      hv[l] = gelu_exact(a);
    }
    float p8[8];
#pragma unroll
    for (int h = 0; h < 8; ++h) {
      float a = 0.f;
#pragma unroll
      for (int l = 0; l < 12; ++l) a += hv[l] * We2[(part * 12 + l) * 9 + h];
      a += __shfl_xor(a, 1, 64);
      a += __shfl_xor(a, 2, 64);
      p8[h] = a + be2[h];
    }
    qk2_s[j][(part << 1) + 0] = p8[(part << 1) + 0];
    qk2_s[j][(part << 1) + 1] = p8[(part << 1) + 1];
  }
  __syncthreads();  // B5

  // ---- phase 4: both softmaxes + gate + coords partial ----
  {
    float qv[8], ge[8];
#pragma unroll
    for (int r = 0; r < 8; ++r) { qv[r] = qk2_s[lane][r]; ge[r] = gelu_exact(qv[r]); }
    float wpart = 0.f;
#pragma unroll
    for (int hh = 0; hh < 2; ++hh) {
      const int h = (wv << 1) + hh;
      float y = qv[h];
      float my = y;
#pragma unroll
      for (int off = 32; off > 0; off >>= 1) my = fmaxf(my, __shfl_xor(my, off, 64));
      const float e2 = __expf(y - my);
      float s2 = e2;
#pragma unroll
      for (int off = 32; off > 0; off >>= 1) s2 += __shfl_xor(s2, off, 64);
      attn_s[lane][h] = e2 / s2;
      float cwv = bcs[h], gt = bgs[h];
#pragma unroll
      for (int r = 0; r < 8; ++r) {
        cwv += ge[r] * Wcs[r * 8 + h];
        gt += qv[r] * Wgs[r * 8 + h];
      }
      gt = tanhf(gt);
      float mx = cwv;
#pragma unroll
      for (int off = 32; off > 0; off >>= 1) mx = fmaxf(mx, __shfl_xor(mx, off, 64));
      const float e = __expf(cwv - mx);
      float sm = e;
#pragma unroll
      for (int off = 32; off > 0; off >>= 1) sm += __shfl_xor(sm, off, 64);
      wpart += (e / sm) * gt * ccs[h];
    }
    float px = wpart * rel_s[lane][0];
    float py = wpart * rel_s[lane][1];
    float pz = wpart * rel_s[lane][2];
#pragma unroll
    for (int off = 32; off > 0; off >>= 1) {
      px += __shfl_xor(px, off, 64);
      py += __shfl_xor(py, off, 64);
      pz += __shfl_xor(pz, off, 64);
    }
    if (lane == 0) { credx[wv][0] = px; credx[wv][1] = py; credx[wv][2] = pz; }
  }
  __syncthreads();  // B6

  if (tid == 0) {
    coors_out[(size_t)row * 3 + 0] = credx[0][0] + credx[1][0] + credx[2][0] + credx[3][0];
    coors_out[(size_t)row * 3 + 1] = credx[0][1] + credx[1][1] + credx[2][1] + credx[3][1];
    coors_out[(size_t)row * 3 + 2] = credx[0][2] + credx[1][2] + credx[2][2] + credx[3][2];
  }

  // ---- phase 5: out[h][2m..2m+1] = sum_j attn[j][h] * rotary(v_fp16[j,h,2m..2m+1]) ----
  {
    const int h = tid >> 5, m = tid & 31;
    const size_t off_v = (size_t)(512 + h * DH + (m << 1));
    float o0 = 0.f, o1 = 0.f;
#pragma unroll 8
    for (int j = 0; j < NB; ++j) {
      const unsigned int vu = *(const unsigned int*)(kvh + ((size_t)b * NPTS + idx_s[j]) * 1024 + off_v);
      const float2 v = h2_to_f2(vu);
      const float2 cs = unpack_cs(cs_s[j][m]);
      const float a = attn_s[j][h];
      o0 += a * (v.x * cs.x - v.y * cs.y);
      o1 += a * (v.y * cs.x + v.x * cs.y);
    }
    *(float2*)(attn_out + (size_t)row * INNER + h * DH + (m << 1)) = make_float2(o0, o1);
  }
}

extern "C" void kernel_launch(void* const* d_in, const int* in_sizes, int n_in,
                              void* d_out, int out_size, void* d_ws, size_t ws_size,
                              hipStream_t stream) {
  const float* feats = (const float*)d_in[0];
  const float* coors = (const float*)d_in[1];
  const float* edges = (const float*)d_in[2];
  const float* W_qkv = (const float*)d_in[3];
  const float* W_out = (const float*)d_in[4];
  const float* b_out = (const float*)d_in[5];
  const float* W_e1 = (const float*)d_in[6];
  const float* b_e1 = (const float*)d_in[7];
  const float* W_e2 = (const float*)d_in[8];
  const float* b_e2 = (const float*)d_in[9];
  const float* W_c = (const float*)d_in[10];
  const float* b_c = (const float*)d_in[11];
  const float* W_g = (const float*)d_in[12];
  const float* b_g = (const float*)d_in[13];
  const float* cc = (const float*)d_in[14];
  const float* cscale = (const float*)d_in[15];

  float* out = (float*)d_out;
  float* qkv = (float*)d_ws;                           // 4096*1536 f32
  float* attn_out = qkv + (size_t)4096 * 1536;         // 4096*512 f32
  __half* kvh = (__half*)(attn_out + (size_t)4096 * 512);  // 4096*1024 f16

  // qkv = feats @ W_qkv (also emits fp16 k,v copies for the gather phases)
  gemm_tiled<<<dim3(24, 64), 256, 0, stream>>>(feats, W_qkv, nullptr, qkv, kvh, 4096, 1536, 256);
  // fused topk + attention
  fused_attn<<<4096, 256, 0, stream>>>(qkv, kvh, coors, edges,
                                       W_e1, b_e1, W_e2, b_e2, W_c, b_c, W_g, b_g,
                                       cc, cscale, attn_out, out + (size_t)4096 * 256);
  // node_out = attn_out @ W_out + b_out
  gemm_tiled<<<dim3(4, 64), 256, 0, stream>>>(attn_out, W_out, b_out, out, nullptr, 4096, 256, 512);
}